// Round 7
// baseline (436.466 us; speedup 1.0000x reference)
//
#include <hip/hip_runtime.h>
#include <hip/hip_bf16.h>

// out = tril((2Q - tril(QK^T)K) K^T) V per (b,h): two fused causal passes of
// Y = tril(X K^T) W  (pass0: X=Q,W=K -> o2; pass1: X=2Q-o2, W=V).
// R5: s-permuted GEMM1 A-reads keep P in registers (no LDS P round-trip);
//     diag-only causal mask; ldsK bit5 col-XOR keeps kf reads 2-way.
// R6: double-buffered K/W tiles -> ONE barrier per iteration; commit at iter
//     bottom.
// R8b/c: wf reads hoisted to regs between GEMM1 and cvt; setprio around MFMA.
// R10: single-strip WGs (1024 = 32 bh x 32 strips), 46 KB LDS -> 3 WGs/CU,
//     longest-first + dynamic backfill, bh = i&31 pins a bh's strips to one
//     XCD (L2 reuse). Confirmed: occupancy 17->25%, 92->79 us.
// R11: 2-deep prefetch. R10 issued tile u+1's loads at iter-u top and waited
//     for them at iter-u bottom -- only the GEMM phase covered the ~200-350cy
//     L2/L3 latency, so the commit's vmcnt wait sat inside the barrier
//     bracket every iteration. Now: iter u issues loads for tile u+2 into reg
//     set [u&1] and commits tile u+1 from reg set [(u+1)&1] -- each load is
//     in flight for a full iteration + GEMM phase (>=2000cy) before its wait.
//     Costs one extra pk/pv reg set (+32 VGPR, ~105 total, still 3+ waves/SIMD).

typedef __bf16 bf16x8 __attribute__((ext_vector_type(8)));
typedef __bf16 bf16x2 __attribute__((ext_vector_type(2)));
typedef float  f32x4  __attribute__((ext_vector_type(4)));

#define MFMA16(a, b, c) __builtin_amdgcn_mfma_f32_16x16x32_bf16((a), (b), (c), 0, 0, 0)

static constexpr int S  = 2048;
static constexpr int H  = 16;
static constexpr int D  = 64;
static constexpr int RS = 3 * H * D;   // 3072 floats between consecutive s rows
static constexpr int BN = 64;          // key rows per iteration
static constexpr int LR = 72;          // row stride (u16): 64 + 8

__global__ __launch_bounds__(256, 3)
void ttt_kernel(const float* __restrict__ qkv, float* __restrict__ out)
{
    __shared__ __bf16 ldsS[64 * LR];      // Q staging -> pass-transition scratch
    __shared__ __bf16 ldsK[2][BN * LR];   // K tile [s][d ^ 32*((s>>3)&1)], x2
    __shared__ __bf16 ldsW[2][D  * LR];   // W^T [d][s ^ (d&56)], x2
    // total 46080 B -> 3 WGs/CU

    const int tid  = threadIdx.x;
    const int wv   = tid >> 6;
    const int lane = tid & 63;
    const int q    = lane >> 4;        // quad 0..3
    const int l16  = lane & 15;

    // mapping: rank = i>>5 ascending => p descending (longest first);
    // bh = i&31 pins all strips of a bh to one XCD (i%8 == bh%8).
    const int i  = (int)blockIdx.x;
    const int p  = 31 - (i >> 5);      // t-strip index, 64-iter strips first
    const int bh = i & 31;
    const int b  = bh >> 4;
    const int h  = bh & 15;
    const int t0 = 64 * p;             // strip rows [t0, t0+64)
    const int nP = p + 1;              // s-blocks per pass

    const float* baseQ = qkv + (size_t)b * S * RS + h * D;
    const float* baseK = baseQ + H * D;
    const float* baseV = baseQ + 2 * H * D;

    // staging coords: thread owns rows r2,r2+1 cols cb..cb+7 of a 64x64 tile
    const int r2  = (tid >> 3) * 2;
    const int cb  = (tid & 7) * 8;
    const int cbK = cb ^ (((r2 >> 3) & 1) << 5);   // ldsK bit5 col swizzle

    f32x4 pk[2][4], pv[2][4];   // 2-deep prefetch reg sets
    auto loadT = [&](f32x4* dst, const float* base, int s0) {
        const float* pg = base + (size_t)(s0 + r2) * RS + cb;
        dst[0] = *(const f32x4*)(pg);
        dst[1] = *(const f32x4*)(pg + 4);
        dst[2] = *(const f32x4*)(pg + RS);
        dst[3] = *(const f32x4*)(pg + RS + 4);
    };

    // commit prefetch regs -> LDS tile buffers (K from ksrc; W from wsrc)
    auto commit = [&](__bf16* K_, __bf16* W_, const f32x4* ksrc, const f32x4* wsrc) {
        bf16x8 w0, w1;
#pragma unroll
        for (int j = 0; j < 4; ++j) {
            w0[j] = (__bf16)ksrc[0][j]; w0[4 + j] = (__bf16)ksrc[1][j];
            w1[j] = (__bf16)ksrc[2][j]; w1[4 + j] = (__bf16)ksrc[3][j];
        }
        *(bf16x8*)(K_ + r2 * LR + cbK)       = w0;
        *(bf16x8*)(K_ + (r2 + 1) * LR + cbK) = w1;
#pragma unroll
        for (int j = 0; j < 8; ++j) {
            const int d = cb + j;
            bf16x2 w;
            w[0] = (__bf16)((j < 4) ? wsrc[0][j & 3] : wsrc[1][j & 3]);
            w[1] = (__bf16)((j < 4) ? wsrc[2][j & 3] : wsrc[3][j & 3]);
            *(bf16x2*)(W_ + d * LR + (r2 ^ (d & 56))) = w;
        }
    };

    // ---- issue tile 0 AND tile 1 loads (both in flight across Q staging) ----
    loadT(pk[0], baseK, 0);            // tile 0 (pass 0: K only)
    if (1 < nP) {                      // tile 1: K tile 1, or pass-1 tile 0
        loadT(pk[1], baseK, 1 * BN);
    } else {
        loadT(pk[1], baseK, 0);
        loadT(pv[1], baseV, 0);
    }

    // ---- stage Q for the strip (64 rows) -> ldsS row-major [t][d] ----
    {
        const int r  = tid >> 2;
        const int cq = (tid & 3) * 16;
        const float* pq = baseQ + (size_t)(t0 + r) * RS + cq;
        __bf16* dst = ldsS + r * LR + cq;
#pragma unroll
        for (int u = 0; u < 2; ++u) {
            f32x4 f0 = *(const f32x4*)(pq + u * 8);
            f32x4 f1 = *(const f32x4*)(pq + u * 8 + 4);
            bf16x8 w;
#pragma unroll
            for (int j = 0; j < 4; ++j) { w[j] = (__bf16)f0[j]; w[4 + j] = (__bf16)f1[j]; }
            *(bf16x8*)(dst + u * 8) = w;
        }
    }

    __syncthreads();   // Q staged

    // ---- hoist X B-frags: lane holds X[t=l16][d=kt*32+q*8+j] ----
    bf16x8 Xf[2];   // [kt]
    const int row0 = wv * 16;
#pragma unroll
    for (int kt = 0; kt < 2; ++kt)
        Xf[kt] = *(bf16x8*)(ldsS + (row0 + l16) * LR + kt * 32 + q * 8);
    __bf16* sc = ldsS + row0 * LR;     // wave-private scratch (16 rows)

    // permuted K-row base: A-row m of tile mi reads physical K row
    //   (mi>>1)*32 + (m>>2)*8 + (mi&1)*4 + (m&3); per-lane part (m = l16):
    const int rp   = (l16 >> 2) * 8 + (l16 & 3);
    const int kcol = (q * 8) | (((l16 >> 2) & 1) << 5);   // disjoint bits

    const f32x4 zero4 = {0.f, 0.f, 0.f, 0.f};
    f32x4 Y[4];
#pragma unroll
    for (int nd = 0; nd < 4; ++nd) Y[nd] = zero4;

    const int tg = t0 + wv * 16 + l16;

    // ---- prologue: commit tile 0 into buf 0 (waits tile-0 loads only;
    //      tile-1 loads are younger and stay in flight) ----
    commit(ldsK[0], ldsW[0], pk[0], pk[0]);
    __syncthreads();                   // buf 0 visible

    const int NT = 2 * nP;             // iterations across both passes

    for (int u = 0; u < NT; ++u) {
        const int c  = u & 1;
        const int sb = (u >= nP) ? (u - nP) : u;

        // ---- issue loads for tile u+2 into reg set [u&1] (free since tile u
        //      was committed from it at the bottom of iter u-1 / prologue) ----
        {
            const int w = u + 2;
            if (w < NT) {
                if (w < nP) {
                    loadT(pk[u & 1], baseK, w * BN);
                } else {
                    loadT(pk[u & 1], baseK, (w - nP) * BN);
                    loadT(pv[u & 1], baseV, (w - nP) * BN);
                }
            }
        }

        __bf16* K_ = ldsK[c];
        __bf16* W_ = ldsW[c];

        // ---- GEMM1-T (s-permuted): Pt[mi][r] = P[s_l][t],
        //      s_l = (mi>>1)*32 + q*8 + (mi&1)*4 + r
        f32x4 Pt[4];
#pragma unroll
        for (int mi = 0; mi < 4; ++mi) Pt[mi] = zero4;
        __builtin_amdgcn_s_setprio(1);
#pragma unroll
        for (int kt = 0; kt < 2; ++kt) {
#pragma unroll
            for (int mi = 0; mi < 4; ++mi) {
                bf16x8 kf = *(bf16x8*)(K_
                    + ((mi >> 1) * 32 + (mi & 1) * 4 + rp) * LR
                    + ((kt * 32) ^ kcol));
                Pt[mi] = MFMA16(kf, Xf[kt], Pt[mi]);
            }
        }
        __builtin_amdgcn_s_setprio(0);

        // ---- hoist wf reads (independent of GEMM1) -> stream under cvt ----
        bf16x8 wfr[2][4];
#pragma unroll
        for (int kt = 0; kt < 2; ++kt)
#pragma unroll
            for (int nd = 0; nd < 4; ++nd) {
                const int d = l16 + nd * 16;
                wfr[kt][nd] = *(bf16x8*)(W_ + d * LR + ((kt * 32 + q * 8) ^ (d & 56)));
            }

        // ---- in-register masked cvt -> GEMM2 A-frags ----
        // af[kt][b2*4+r] = P[t=l16][s = kt*32 + q*8 + b2*4 + r] (masked)
        bf16x8 af[2];
        {
            const bool diag = (sb == nP - 1);
#pragma unroll
            for (int kt = 0; kt < 2; ++kt) {
                bf16x8 a;
                if (diag) {
#pragma unroll
                    for (int b2 = 0; b2 < 2; ++b2)
#pragma unroll
                        for (int r = 0; r < 4; ++r) {
                            const int sg = sb * BN + kt * 32 + q * 8 + b2 * 4 + r;
                            a[b2 * 4 + r] = (sg <= tg) ? (__bf16)Pt[2 * kt + b2][r]
                                                       : (__bf16)0.0f;
                        }
                } else {
#pragma unroll
                    for (int b2 = 0; b2 < 2; ++b2)
#pragma unroll
                        for (int r = 0; r < 4; ++r)
                            a[b2 * 4 + r] = (__bf16)Pt[2 * kt + b2][r];
                }
                af[kt] = a;
            }
        }

        // ---- GEMM2: Y[t][d] += sum_s P[t][s] W[s][d] ----
        __builtin_amdgcn_s_setprio(1);
#pragma unroll
        for (int kt = 0; kt < 2; ++kt)
#pragma unroll
            for (int nd = 0; nd < 4; ++nd)
                Y[nd] = MFMA16(af[kt], wfr[kt][nd], Y[nd]);
        __builtin_amdgcn_s_setprio(0);

        // ---- pass seam / epilogue (wave-private LDS scratch or stores) ----
        if (u == nP - 1) {
            // o2 (C-layout) -> scratch plain [t][d], reread as frags,
            // Xf = 2Q - o2; then reset Y.
#pragma unroll
            for (int nd = 0; nd < 4; ++nd)
#pragma unroll
                for (int r = 0; r < 4; ++r)
                    sc[(q * 4 + r) * LR + l16 + nd * 16] = (__bf16)Y[nd][r];
#pragma unroll
            for (int kt = 0; kt < 2; ++kt) {
                bf16x8 of = *(bf16x8*)(sc + l16 * LR + kt * 32 + q * 8);
#pragma unroll
                for (int j = 0; j < 8; ++j)
                    Xf[kt][j] = (__bf16)(2.0f * (float)Xf[kt][j] - (float)of[j]);
            }
#pragma unroll
            for (int nd = 0; nd < 4; ++nd) Y[nd] = zero4;
        } else if (u == NT - 1) {
            // out[b][t][h][d] fp32
#pragma unroll
            for (int nd = 0; nd < 4; ++nd)
#pragma unroll
                for (int r = 0; r < 4; ++r) {
                    const int t = t0 + wv * 16 + q * 4 + r;
                    const int d = l16 + nd * 16;
                    out[(((size_t)b * S + t) * H + h) * D + d] = Y[nd][r];
                }
        }

        // ---- pack tile u+1 (loaded 1.5 iters ago) into the other buffer ----
        if (u + 1 < NT) {
            const int w = u + 1;
            commit(ldsK[1 - c], ldsW[1 - c], pk[w & 1],
                   (w >= nP) ? pv[w & 1] : pk[w & 1]);
            __syncthreads();
        }
    }
}

extern "C" void kernel_launch(void* const* d_in, const int* in_sizes, int n_in,
                              void* d_out, int out_size, void* d_ws, size_t ws_size,
                              hipStream_t stream)
{
    const float* qkv = (const float*)d_in[0];
    float* out = (float*)d_out;
    ttt_kernel<<<dim3(1024), 256, 0, stream>>>(qkv, out);   // 32 strips x 32 bh
}

// Round 8
// 150.957 us; speedup vs baseline: 2.8913x; 2.8913x over previous
//
#include <hip/hip_runtime.h>
#include <hip/hip_bf16.h>

// out = tril((2Q - tril(QK^T)K) K^T) V per (b,h): two fused causal passes of
// Y = tril(X K^T) W  (pass0: X=Q,W=K -> o2; pass1: X=2Q-o2, W=V).
// R5: s-permuted GEMM1 A-reads keep P in registers (no LDS P round-trip);
//     diag-only causal mask; ldsK bit5 col-XOR keeps kf reads 2-way.
// R6: double-buffered K/W tiles -> ONE barrier per iteration; commit at iter
//     bottom.
// R8b/c: wf reads hoisted to regs between GEMM1 and cvt; setprio around MFMA.
// R10: single-strip WGs (1024 = 32 bh x 32 strips), 46 KB LDS -> 3 WGs/CU,
//     longest-first + dynamic backfill, bh = i&31 pins a bh's strips to one
//     XCD (L2 reuse). Confirmed: occupancy 17->25%, 92->79 us.
// R11: 2-deep prefetch (tile u+2 issued at iter-u top) -- REGRESSED 4.7x:
//     pk[u&1] runtime index demoted both reg-sets to scratch (rule #20;
//     WRITE_SIZE 16->807 MB, VGPR 100->68 = the fingerprint).
// R12: same 2-deep schedule, STATIC indexing. Main loop unrolled 2x (NT is
//     always even): named reg-sets pk0/pv0 (even tiles) and pk1/pv1 (odd
//     tiles), literal LDS buffer indices (even sub-iter buf0, odd buf1).
//     Every array access compile-time constant -> SROA keeps regs (the
//     pattern R10 proved at VGPR 72). Loads are in flight a full iteration
//     + GEMM phase before their commit-side vmcnt wait.

typedef __bf16 bf16x8 __attribute__((ext_vector_type(8)));
typedef __bf16 bf16x2 __attribute__((ext_vector_type(2)));
typedef float  f32x4  __attribute__((ext_vector_type(4)));

#define MFMA16(a, b, c) __builtin_amdgcn_mfma_f32_16x16x32_bf16((a), (b), (c), 0, 0, 0)

static constexpr int S  = 2048;
static constexpr int H  = 16;
static constexpr int D  = 64;
static constexpr int RS = 3 * H * D;   // 3072 floats between consecutive s rows
static constexpr int BN = 64;          // key rows per iteration
static constexpr int LR = 72;          // row stride (u16): 64 + 8

__global__ __launch_bounds__(256, 3)
void ttt_kernel(const float* __restrict__ qkv, float* __restrict__ out)
{
    __shared__ __bf16 ldsS[64 * LR];      // Q staging -> pass-transition scratch
    __shared__ __bf16 ldsK[2][BN * LR];   // K tile [s][d ^ 32*((s>>3)&1)], x2
    __shared__ __bf16 ldsW[2][D  * LR];   // W^T [d][s ^ (d&56)], x2
    // total 46080 B -> 3 WGs/CU

    const int tid  = threadIdx.x;
    const int wv   = tid >> 6;
    const int lane = tid & 63;
    const int q    = lane >> 4;        // quad 0..3
    const int l16  = lane & 15;

    // mapping: rank = i>>5 ascending => p descending (longest first);
    // bh = i&31 pins all strips of a bh to one XCD (i%8 == bh%8).
    const int i  = (int)blockIdx.x;
    const int p  = 31 - (i >> 5);      // t-strip index, 64-iter strips first
    const int bh = i & 31;
    const int b  = bh >> 4;
    const int h  = bh & 15;
    const int t0 = 64 * p;             // strip rows [t0, t0+64)
    const int nP = p + 1;              // s-blocks per pass

    const float* baseQ = qkv + (size_t)b * S * RS + h * D;
    const float* baseK = baseQ + H * D;
    const float* baseV = baseQ + 2 * H * D;

    // staging coords: thread owns rows r2,r2+1 cols cb..cb+7 of a 64x64 tile
    const int r2  = (tid >> 3) * 2;
    const int cb  = (tid & 7) * 8;
    const int cbK = cb ^ (((r2 >> 3) & 1) << 5);   // ldsK bit5 col swizzle

    // R12: named 2-deep prefetch reg sets -- ALL accesses literal-indexed.
    f32x4 pk0[4], pk1[4], pv0[4], pv1[4];
    auto loadT = [&](f32x4* dst, const float* base, int s0) {
        const float* pg = base + (size_t)(s0 + r2) * RS + cb;
        dst[0] = *(const f32x4*)(pg);
        dst[1] = *(const f32x4*)(pg + 4);
        dst[2] = *(const f32x4*)(pg + RS);
        dst[3] = *(const f32x4*)(pg + RS + 4);
    };

    // commit prefetch regs -> LDS tile buffers (K from ksrc; W from wsrc)
    auto commit = [&](__bf16* K_, __bf16* W_, const f32x4* ksrc, const f32x4* wsrc) {
        bf16x8 w0, w1;
#pragma unroll
        for (int j = 0; j < 4; ++j) {
            w0[j] = (__bf16)ksrc[0][j]; w0[4 + j] = (__bf16)ksrc[1][j];
            w1[j] = (__bf16)ksrc[2][j]; w1[4 + j] = (__bf16)ksrc[3][j];
        }
        *(bf16x8*)(K_ + r2 * LR + cbK)       = w0;
        *(bf16x8*)(K_ + (r2 + 1) * LR + cbK) = w1;
#pragma unroll
        for (int j = 0; j < 8; ++j) {
            const int d = cb + j;
            bf16x2 w;
            w[0] = (__bf16)((j < 4) ? wsrc[0][j & 3] : wsrc[1][j & 3]);
            w[1] = (__bf16)((j < 4) ? wsrc[2][j & 3] : wsrc[3][j & 3]);
            *(bf16x2*)(W_ + d * LR + (r2 ^ (d & 56))) = w;
        }
    };

    // ---- issue tile 0 AND tile 1 loads (both in flight across Q staging) ----
    loadT(pk0, baseK, 0);              // tile 0 (pass 0: K only)
    if (1 < nP) {                      // tile 1: K tile 1, or pass-1 tile 0
        loadT(pk1, baseK, 1 * BN);
    } else {
        loadT(pk1, baseK, 0);
        loadT(pv1, baseV, 0);
    }

    // ---- stage Q for the strip (64 rows) -> ldsS row-major [t][d] ----
    {
        const int r  = tid >> 2;
        const int cq = (tid & 3) * 16;
        const float* pq = baseQ + (size_t)(t0 + r) * RS + cq;
        __bf16* dst = ldsS + r * LR + cq;
#pragma unroll
        for (int u = 0; u < 2; ++u) {
            f32x4 f0 = *(const f32x4*)(pq + u * 8);
            f32x4 f1 = *(const f32x4*)(pq + u * 8 + 4);
            bf16x8 w;
#pragma unroll
            for (int j = 0; j < 4; ++j) { w[j] = (__bf16)f0[j]; w[4 + j] = (__bf16)f1[j]; }
            *(bf16x8*)(dst + u * 8) = w;
        }
    }

    __syncthreads();   // Q staged

    // ---- hoist X B-frags: lane holds X[t=l16][d=kt*32+q*8+j] ----
    bf16x8 Xf[2];   // [kt]
    const int row0 = wv * 16;
#pragma unroll
    for (int kt = 0; kt < 2; ++kt)
        Xf[kt] = *(bf16x8*)(ldsS + (row0 + l16) * LR + kt * 32 + q * 8);
    __bf16* sc = ldsS + row0 * LR;     // wave-private scratch (16 rows)

    // permuted K-row base: A-row m of tile mi reads physical K row
    //   (mi>>1)*32 + (m>>2)*8 + (mi&1)*4 + (m&3); per-lane part (m = l16):
    const int rp   = (l16 >> 2) * 8 + (l16 & 3);
    const int kcol = (q * 8) | (((l16 >> 2) & 1) << 5);   // disjoint bits

    const f32x4 zero4 = {0.f, 0.f, 0.f, 0.f};
    f32x4 Y[4];
#pragma unroll
    for (int nd = 0; nd < 4; ++nd) Y[nd] = zero4;

    const int tg = t0 + wv * 16 + l16;
    const int NT = 2 * nP;             // iterations across both passes (even)

    // ---- prologue: commit tile 0 into buf 0 (waits tile-0 loads only;
    //      tile-1 loads are younger and stay in flight) ----
    commit(ldsK[0], ldsW[0], pk0, pk0);
    __syncthreads();                   // buf 0 visible

    // one GEMM+seam/epilogue step on a given buffer (u is runtime; all reg
    // arrays literal-indexed inside)
    auto gemmIter = [&](int u, __bf16* K_, __bf16* W_) {
        const int sb = (u >= nP) ? (u - nP) : u;

        // ---- GEMM1-T (s-permuted): Pt[mi][r] = P[s_l][t],
        //      s_l = (mi>>1)*32 + q*8 + (mi&1)*4 + r
        f32x4 Pt[4];
#pragma unroll
        for (int mi = 0; mi < 4; ++mi) Pt[mi] = zero4;
        __builtin_amdgcn_s_setprio(1);
#pragma unroll
        for (int kt = 0; kt < 2; ++kt) {
#pragma unroll
            for (int mi = 0; mi < 4; ++mi) {
                bf16x8 kf = *(bf16x8*)(K_
                    + ((mi >> 1) * 32 + (mi & 1) * 4 + rp) * LR
                    + ((kt * 32) ^ kcol));
                Pt[mi] = MFMA16(kf, Xf[kt], Pt[mi]);
            }
        }
        __builtin_amdgcn_s_setprio(0);

        // ---- hoist wf reads (independent of GEMM1) -> stream under cvt ----
        bf16x8 wfr[2][4];
#pragma unroll
        for (int kt = 0; kt < 2; ++kt)
#pragma unroll
            for (int nd = 0; nd < 4; ++nd) {
                const int d = l16 + nd * 16;
                wfr[kt][nd] = *(bf16x8*)(W_ + d * LR + ((kt * 32 + q * 8) ^ (d & 56)));
            }

        // ---- in-register masked cvt -> GEMM2 A-frags ----
        // af[kt][b2*4+r] = P[t=l16][s = kt*32 + q*8 + b2*4 + r] (masked)
        bf16x8 af[2];
        {
            const bool diag = (sb == nP - 1);
#pragma unroll
            for (int kt = 0; kt < 2; ++kt) {
                bf16x8 a;
                if (diag) {
#pragma unroll
                    for (int b2 = 0; b2 < 2; ++b2)
#pragma unroll
                        for (int r = 0; r < 4; ++r) {
                            const int sg = sb * BN + kt * 32 + q * 8 + b2 * 4 + r;
                            a[b2 * 4 + r] = (sg <= tg) ? (__bf16)Pt[2 * kt + b2][r]
                                                       : (__bf16)0.0f;
                        }
                } else {
#pragma unroll
                    for (int b2 = 0; b2 < 2; ++b2)
#pragma unroll
                        for (int r = 0; r < 4; ++r)
                            a[b2 * 4 + r] = (__bf16)Pt[2 * kt + b2][r];
                }
                af[kt] = a;
            }
        }

        // ---- GEMM2: Y[t][d] += sum_s P[t][s] W[s][d] ----
        __builtin_amdgcn_s_setprio(1);
#pragma unroll
        for (int kt = 0; kt < 2; ++kt)
#pragma unroll
            for (int nd = 0; nd < 4; ++nd)
                Y[nd] = MFMA16(af[kt], wfr[kt][nd], Y[nd]);
        __builtin_amdgcn_s_setprio(0);

        // ---- pass seam / epilogue (wave-private LDS scratch or stores) ----
        if (u == nP - 1) {
            // o2 (C-layout) -> scratch plain [t][d], reread as frags,
            // Xf = 2Q - o2; then reset Y.
#pragma unroll
            for (int nd = 0; nd < 4; ++nd)
#pragma unroll
                for (int r = 0; r < 4; ++r)
                    sc[(q * 4 + r) * LR + l16 + nd * 16] = (__bf16)Y[nd][r];
#pragma unroll
            for (int kt = 0; kt < 2; ++kt) {
                bf16x8 of = *(bf16x8*)(sc + l16 * LR + kt * 32 + q * 8);
#pragma unroll
                for (int j = 0; j < 8; ++j)
                    Xf[kt][j] = (__bf16)(2.0f * (float)Xf[kt][j] - (float)of[j]);
            }
#pragma unroll
            for (int nd = 0; nd < 4; ++nd) Y[nd] = zero4;
        } else if (u == NT - 1) {
            // out[b][t][h][d] fp32
#pragma unroll
            for (int nd = 0; nd < 4; ++nd)
#pragma unroll
                for (int r = 0; r < 4; ++r) {
                    const int t = t0 + wv * 16 + q * 4 + r;
                    const int d = l16 + nd * 16;
                    out[(((size_t)b * S + t) * H + h) * D + d] = Y[nd][r];
                }
        }
    };

    // ---- main loop, 2x unrolled: even tiles <-> set0/buf0, odd <-> set1/buf1
    for (int u = 0; u < NT; u += 2) {
        // === even sub-iter u: read buf0; issue tile u+2 -> set0;
        //     commit tile u+1 from set1 -> buf1 ===
        {
            const int w = u + 2;
            if (w < NT) {
                if (w < nP) {
                    loadT(pk0, baseK, w * BN);
                } else {
                    loadT(pk0, baseK, (w - nP) * BN);
                    loadT(pv0, baseV, (w - nP) * BN);
                }
            }
        }
        gemmIter(u, ldsK[0], ldsW[0]);
        {
            const int w = u + 1;       // always < NT (u <= NT-2, NT even)
            commit(ldsK[1], ldsW[1], pk1, (w >= nP) ? pv1 : pk1);
            __syncthreads();
        }

        // === odd sub-iter u+1: read buf1; issue tile u+3 -> set1;
        //     commit tile u+2 from set0 -> buf0 ===
        {
            const int w = u + 3;
            if (w < NT) {
                if (w < nP) {
                    loadT(pk1, baseK, w * BN);
                } else {
                    loadT(pk1, baseK, (w - nP) * BN);
                    loadT(pv1, baseV, (w - nP) * BN);
                }
            }
        }
        gemmIter(u + 1, ldsK[1], ldsW[1]);
        {
            const int w = u + 2;
            if (w < NT) {
                commit(ldsK[0], ldsW[0], pk0, (w >= nP) ? pv0 : pk0);
                __syncthreads();
            }
        }
    }
}

extern "C" void kernel_launch(void* const* d_in, const int* in_sizes, int n_in,
                              void* d_out, int out_size, void* d_ws, size_t ws_size,
                              hipStream_t stream)
{
    const float* qkv = (const float*)d_in[0];
    float* out = (float*)d_out;
    ttt_kernel<<<dim3(1024), 256, 0, stream>>>(qkv, out);   // 32 strips x 32 bh
}